// Round 1
// baseline (1358.976 us; speedup 1.0000x reference)
//
#include <hip/hip_runtime.h>
#include <cstddef>

// Problem constants (reference: B=8, S=512, E=128, H=512, ENC=128)
#define BB 8
#define SS 512
#define EE 128
#define HH 512
#define ENC 128

// ---------------------------------------------------------------------------
// Bit-exact emulation of XLA CPU's EmitTanh (verified bitwise r6..r15).
// All ops rn, NON-fused. __f*_rn intrinsics block compiler contraction.
// NOTE (r8): packed v_pk_* fp32 is NOT bit-identical on gfx950 — scalar only.
// ---------------------------------------------------------------------------
__device__ __forceinline__ float xla_tanhf(float x) {
    const float cx = fminf(fmaxf(x, -9.0f), 9.0f);
    const float x2 = __fmul_rn(cx, cx);
    float p = -2.76076847742355e-16f;
    p = __fadd_rn(__fmul_rn(p, x2), 2.00018790482477e-13f);
    p = __fadd_rn(__fmul_rn(p, x2), -8.60467152213735e-11f);
    p = __fadd_rn(__fmul_rn(p, x2), 5.12229709037114e-08f);
    p = __fadd_rn(__fmul_rn(p, x2), 1.48572235717979e-05f);
    p = __fadd_rn(__fmul_rn(p, x2), 6.37261928875436e-04f);
    p = __fadd_rn(__fmul_rn(p, x2), 4.89352455891786e-03f);
    const float num = __fmul_rn(cx, p);
    float q = 1.19825839466702e-06f;
    q = __fadd_rn(__fmul_rn(q, x2), 1.18534705686654e-04f);
    q = __fadd_rn(__fmul_rn(q, x2), 2.26843463243900e-03f);
    q = __fadd_rn(__fmul_rn(q, x2), 4.89352518554385e-03f);
    const float r = __fdiv_rn(num, q);
    return (fabsf(x) < 0.0004f) ? x : r;
}

// Map a packed chunk-row m -> global action row:
//   b = m >> chsh (CH = chm1+1), global row = b*SS + i0 + (m & chm1)
__device__ __forceinline__ int arow_map(int m, int chm1, int chsh, int i0) {
    return ((m >> chsh) * SS) + i0 + (m & chm1);
}

// ---------------------------------------------------------------------------
// Tiled GEMM body, bitwise-preserving XLA-CPU dot semantics (VERIFIED
// r6..r15 — scalar v_mul/v_add only). K-chain: one accumulator per element,
// k0 tiles ascend, inner k ascends — DO NOT TOUCH.
//
// TRANSP=1 (GEMM2 only): block bx covers B-rows o = d*128+e with
// d in [16*bd,16*bd+16), e in [8*be,8*be+8)  (bd=bx>>4, be=bx&15).
// Epilogue stores the d-INTERLEAVED layout:
//   Wa4[m][(d>>2)*128 + e] as float4 component (d&3)
// so the scan's quarter loads are lane-consecutive float4 (r15-proven).
// Values bit-identical; address-only.
//
// Factored as a __device__ body so both the standalone kernel and the
// combined gemm2+scan kernel use the IDENTICAL instruction sequence.
// ---------------------------------------------------------------------------
template <int ACT, int MAPROW, int TRANSP>
__device__ __forceinline__ void gemm_body(const float* __restrict__ A,
                                          const float* __restrict__ Bm,
                                          const float* __restrict__ bias,
                                          float* __restrict__ C,
                                          int N, int K,
                                          int chm1, int chsh, int i0,
                                          int bx, int by,
                                          float (*As)[128], float (*Bs)[128]) {
    const int tid = threadIdx.x;
    const int tx = tid & 15;   // n-direction (8 cols each)
    const int ty = tid >> 4;   // m-direction (8 rows each)
    const int n0 = bx * 128;
    const int m0 = by * 128;
    const int bd = bx >> 4;   // TRANSP: d-tile (0..7)
    const int be = bx & 15;   // TRANSP: e-tile (0..15)

    const int lr = tid >> 2;          // 0..63 (row within tile)
    const int lc = (tid & 3) << 2;    // 0,4,8,12 (col within K-tile)

    const int ga0 = MAPROW ? arow_map(m0 + lr, chm1, chsh, i0) : (m0 + lr);
    const int ga1 = MAPROW ? arow_map(m0 + lr + 64, chm1, chsh, i0) : (m0 + lr + 64);

    // B-row indices for the two loader rows (identity unless TRANSP)
    const int r0 = lr, r1 = lr + 64;
    const int gb0 = TRANSP ? ((bd * 16 + (r0 >> 3)) * 128 + be * 8 + (r0 & 7))
                           : (n0 + r0);
    const int gb1 = TRANSP ? ((bd * 16 + (r1 >> 3)) * 128 + be * 8 + (r1 & 7))
                           : (n0 + r1);

    float acc[8][8];
#pragma unroll
    for (int i = 0; i < 8; ++i)
#pragma unroll
        for (int j = 0; j < 8; ++j) acc[i][j] = 0.f;

    for (int k0 = 0; k0 < K; k0 += 16) {
        const float4 a0 = *(const float4*)(A + (size_t)ga0 * K + (k0 + lc));
        const float4 a1 = *(const float4*)(A + (size_t)ga1 * K + (k0 + lc));
        const float4 b0 = *(const float4*)(Bm + (size_t)gb0 * K + (k0 + lc));
        const float4 b1 = *(const float4*)(Bm + (size_t)gb1 * K + (k0 + lc));

        __syncthreads();  // previous iteration's compute done before overwrite

        As[lc + 0][lr] = a0.x; As[lc + 1][lr] = a0.y;
        As[lc + 2][lr] = a0.z; As[lc + 3][lr] = a0.w;
        As[lc + 0][lr + 64] = a1.x; As[lc + 1][lr + 64] = a1.y;
        As[lc + 2][lr + 64] = a1.z; As[lc + 3][lr + 64] = a1.w;
        Bs[lc + 0][lr] = b0.x; Bs[lc + 1][lr] = b0.y;
        Bs[lc + 2][lr] = b0.z; Bs[lc + 3][lr] = b0.w;
        Bs[lc + 0][lr + 64] = b1.x; Bs[lc + 1][lr + 64] = b1.y;
        Bs[lc + 2][lr + 64] = b1.z; Bs[lc + 3][lr + 64] = b1.w;

        __syncthreads();

#pragma unroll
        for (int k = 0; k < 16; ++k) {   // ascending k within tile
            const float4 av0 = *(const float4*)&As[k][ty * 8];
            const float4 av1 = *(const float4*)&As[k][ty * 8 + 4];
            const float4 bv0 = *(const float4*)&Bs[k][tx * 8];
            const float4 bv1 = *(const float4*)&Bs[k][tx * 8 + 4];
            const float a[8] = {av0.x, av0.y, av0.z, av0.w, av1.x, av1.y, av1.z, av1.w};
            const float b[8] = {bv0.x, bv0.y, bv0.z, bv0.w, bv1.x, bv1.y, bv1.z, bv1.w};
#pragma unroll
            for (int i = 0; i < 8; ++i)
#pragma unroll
                for (int j = 0; j < 8; ++j)
                    acc[i][j] = __fadd_rn(acc[i][j], __fmul_rn(a[i], b[j]));
        }
    }

    // epilogue: + bias (after full k-chain), optional XLA tanh, store
#pragma unroll
    for (int i = 0; i < 8; ++i) {
        const int m = m0 + ty * 8 + i;
        if (TRANSP) {
            // acc[i][j] is element o = d*128 + e, d = bd*16+tx, e = be*8+j.
            // d-interleaved store: C[m][((d>>2)*128 + e)*4 + (d&3)]
            const int d = bd * 16 + tx;
#pragma unroll
            for (int j = 0; j < 8; ++j) {
                const int ee = be * 8 + j;
                const int o = d * 128 + ee;
                const float v = __fadd_rn(acc[i][j], bias[o]);
                C[(size_t)m * N + ((size_t)(d >> 2) * 128 + ee) * 4 + (d & 3)] = v;
            }
        } else {
            float v[8];
#pragma unroll
            for (int j = 0; j < 8; ++j) {
                const int n = n0 + tx * 8 + j;
                v[j] = __fadd_rn(acc[i][j], bias[n]);
                if (ACT) v[j] = xla_tanhf(v[j]);
            }
            float4* dst = (float4*)(C + (size_t)m * N + (n0 + tx * 8));
            dst[0] = make_float4(v[0], v[1], v[2], v[3]);
            dst[1] = make_float4(v[4], v[5], v[6], v[7]);
        }
    }
}

template <int ACT, int MAPROW, int TRANSP>
__global__ __launch_bounds__(256) void gemm_nt(const float* __restrict__ A,
                                               const float* __restrict__ Bm,
                                               const float* __restrict__ bias,
                                               float* __restrict__ C,
                                               int N, int K,
                                               int chm1, int chsh, int i0) {
    __shared__ float As[16][128];
    __shared__ float Bs[16][128];
    gemm_body<ACT, MAPROW, TRANSP>(A, Bm, bias, C, N, K, chm1, chsh, i0,
                                   blockIdx.x, blockIdx.y, As, Bs);
}

// ---------------------------------------------------------------------------
// Sequential attractor scan body over d-interleaved Wa4 (r16 structure,
// verbatim: unconditional clamped prefetch, quarter-grain pipeline distance 3
// (4 x 8 float4 = 128 VGPRs), ping-pong et, ONE barrier/step).
// Chain is op-for-op the verified sequence: ONE accumulator, strictly
// ascending d (q asc, dq asc, x,y,z,w = d..d+3), non-fused
// __fmul_rn/__fadd_rn — bitwise contract.
//
// Factored as a __device__ body callable from blocks with 128 OR 256 threads:
// threads >= 128 are inactive but execute the SAME uniform barrier sequence
// (barriers are outside all act-guards; loop bounds are block-uniform).
// ---------------------------------------------------------------------------
__device__ __forceinline__ void scan_body(const float* __restrict__ Wa,
                                          const float* __restrict__ e0,
                                          float* __restrict__ et_state,
                                          float* __restrict__ out,
                                          int i0, int CH, int b,
                                          float (*et)[128]) {
    const int tid = threadIdx.x;
    const bool act = tid < 128;
    const int e = tid & 127;  // 0..127 (output coord for active threads)

    int s = 0;
    if (act) {
        if (i0 == 0) {
            const float v = e0[e];
            et[0][e] = v;
            out[(size_t)b * SS * ENC + e] = v;
        } else {
            et[0][e] = et_state[b * 128 + e];
        }
    }
    __syncthreads();

    const int start = (i0 == 0) ? 1 : 0;
    const float4* Wb4 = (const float4*)(Wa + (size_t)b * CH * (ENC * ENC));
    const int nq = (CH - start) * 4;   // total quarter-tiles this launch
    // step stride in float4 units: ENC*ENC/4 = 4096; quarter stride: 8*128=1024

    float4 w4[4][8];   // 4 quarter buffers x 8 float4 = 128 VGPRs

    // preload quarters 0,1,2 of step `start`
    if (act) {
        const float4* S4 = Wb4 + (size_t)start * 4096 + e;
#pragma unroll
        for (int u = 0; u < 8; ++u) w4[0][u] = S4[u * 128];
#pragma unroll
        for (int u = 0; u < 8; ++u) w4[1][u] = S4[(8 + u) * 128];
#pragma unroll
        for (int u = 0; u < 8; ++u) w4[2][u] = S4[(16 + u) * 128];
    }
    asm volatile("" ::: "memory");  // loads pinned before first chain

    for (int ii = start; ii < CH; ++ii) {
        if (act) {
            float sum = 0.f;   // ONE accumulator, ascending d across all quarters
#pragma unroll
            for (int q = 0; q < 4; ++q) {
                // UNCONDITIONAL prefetch for quarter pf (clamped): straight-line
                // loads -> precise vmcnt. Clamped (pf>=nq) loads land in buffers
                // never consumed.
                const int pf = (ii - start) * 4 + q + 3;
                const int pfc = (pf < nq) ? pf : (nq - 1);   // uniform select
                const float4* P4 = Wb4 + (size_t)(start + (pfc >> 2)) * 4096
                                       + (size_t)(pfc & 3) * 1024 + e;
#pragma unroll
                for (int u = 0; u < 8; ++u) w4[(q + 3) & 3][u] = P4[u * 128];
                asm volatile("" ::: "memory");
                // consume quarter q: d = 32q .. 32q+31, strictly ascending
#pragma unroll
                for (int dq = 0; dq < 8; ++dq) {
                    const float4 t4 = *(const float4*)&et[s][q * 32 + dq * 4];
                    const float4 wv = w4[q][dq];   // W[d..d+3][e], d = 32q+4dq
                    sum = __fadd_rn(sum, __fmul_rn(t4.x, wv.x));
                    sum = __fadd_rn(sum, __fmul_rn(t4.y, wv.y));
                    sum = __fadd_rn(sum, __fmul_rn(t4.z, wv.z));
                    sum = __fadd_rn(sum, __fmul_rn(t4.w, wv.w));
                }
            }
            const float v = fminf(fmaxf(sum, -5.f), 5.f);  // jnp.clip
            out[((size_t)b * SS + (i0 + ii)) * ENC + e] = v;
            et[s ^ 1][e] = v;   // this step's readers use et[s] — no conflict
        }
        __syncthreads();    // publishes et[s^1]; orders next step's overwrite
        s ^= 1;
    }
    if (act) et_state[b * 128 + e] = et[s][e];
}

// Standalone scan (used for the LAST chunk, nothing to overlap with):
// keeps the r16 launch config untouched (128 threads, 1 block/CU).
__global__ __launch_bounds__(128, 1) void scan_kernel(const float* __restrict__ Wa,
                                                      const float* __restrict__ e0,
                                                      float* __restrict__ et_state,
                                                      float* __restrict__ out,
                                                      int i0, int CH) {
    __shared__ float et[2][128];
    scan_body(Wa, e0, et_state, out, i0, CH, blockIdx.x, et);
}

// ---------------------------------------------------------------------------
// r17: launch-level software pipeline. One combined kernel runs
//   blocks 0..7              : scan of chunk c  (reads WaSrc; prio-boosted)
//   blocks 8..8+128*Mc/128-1 : GEMM2 of chunk c+1 (writes WaDst)
// The two halves are fully independent (scan c needs only Wa(c), written by
// the PREVIOUS launch; GEMM2 c+1 needs only hidden, written up front), so
// correctness does not depend on dispatch order / placement (Guideline 16).
// Scan blocks are at blockIdx.x<8 so they dispatch first; their waves run at
// s_setprio(2) so the latency-critical serial chain wins VALU arbitration
// against co-resident GEMM2 waves (T5 mechanism: wave role diversity).
// Values bit-identical to the serial schedule — overlap only.
// ---------------------------------------------------------------------------
__global__ __launch_bounds__(256, 2) void gemm2_scan(
        const float* __restrict__ hidden, const float* __restrict__ W2,
        const float* __restrict__ b2, float* __restrict__ WaDst,
        const float* __restrict__ WaSrc, const float* __restrict__ e0,
        float* __restrict__ et_state, float* __restrict__ out,
        int chm1, int chsh, int i0_g2, int i0_scan, int CH) {
    __shared__ float As[16][128];
    __shared__ float Bs[16][128];
    __shared__ float et[2][128];

    if (blockIdx.x < 8) {
        if (blockIdx.y != 0) return;   // only the y==0 row carries scan blocks
        __builtin_amdgcn_s_setprio(2); // favor the serial chain on shared CUs
        scan_body(WaSrc, e0, et_state, out, i0_scan, CH, blockIdx.x, et);
        return;
    }
    gemm_body<0, 1, 1>(hidden, W2, b2, WaDst, ENC * ENC, HH,
                       chm1, chsh, i0_g2, blockIdx.x - 8, blockIdx.y, As, Bs);
}

// ---------------------------------------------------------------------------
extern "C" void kernel_launch(void* const* d_in, const int* in_sizes, int n_in,
                              void* d_out, int out_size, void* d_ws, size_t ws_size,
                              hipStream_t stream) {
    const float* A  = (const float*)d_in[0];  // (B,S,E)   = (8,512,128) fp32
    const float* W1 = (const float*)d_in[1];  // (H,E)     = (512,128)  fp32
    const float* b1 = (const float*)d_in[2];  // (H,)      fp32
    const float* W2 = (const float*)d_in[3];  // (ENC*ENC,H) = (16384,512) fp32
    const float* b2 = (const float*)d_in[4];  // (ENC*ENC,) fp32
    const float* e0 = (const float*)d_in[5];  // (1,ENC)   fp32
    float* out = (float*)d_out;               // (B,S,ENC) fp32

    const size_t hid_bytes = (size_t)BB * SS * HH * sizeof(float);  // 8 MB

    // Pipelined path: full hidden + DOUBLE-buffered Wa chunks.
    // CH=64 preferred: 8 chunks -> small exposed ends (first GEMM2 ~110us,
    // last scan ~70us); needs 4KB + 8MB + 2*33.6MB = 75MB (ws >= ~138MB
    // known from the prior CH=256 run). Smaller CH only as a guard.
    int CH = 0;
    for (int c = 64; c >= 16; c >>= 1) {
        const size_t chunk_bytes = (size_t)BB * c * (size_t)(ENC * ENC) * sizeof(float);
        if (4096 + hid_bytes + 2 * chunk_bytes <= ws_size) { CH = c; break; }
    }

    if (CH != 0) {
        const int Mc = BB * CH;
        int chsh = 0;
        while ((1 << chsh) < CH) ++chsh;
        const int chm1 = CH - 1;
        const int n = SS / CH;

        float* et_state = (float*)d_ws;
        float* hidden   = (float*)((char*)d_ws + 4096);
        float* Wa0 = hidden + (size_t)BB * SS * HH;
        float* Wa1 = Wa0 + (size_t)Mc * (ENC * ENC);
        float* Wab[2] = {Wa0, Wa1};

        // GEMM1 once, full S: hidden[b*512+s][h] = tanh(A @ W1^T + b1)
        dim3 g1(HH / 128, (BB * SS) / 128);
        gemm_nt<1, 0, 0><<<g1, 256, 0, stream>>>(A, W1, b1, hidden, HH, EE,
                                                 0, 0, 0);
        // GEMM2 chunk 0 (nothing to overlap with yet)
        dim3 g2((ENC * ENC) / 128, Mc / 128);
        gemm_nt<0, 1, 1><<<g2, 256, 0, stream>>>(hidden, W2, b2, Wa0,
                                                 ENC * ENC, HH, chm1, chsh, 0);
        // Pipeline: launch L_c = { scan chunk c  ||  GEMM2 chunk c+1 }.
        // Same-stream serialization guarantees Wa(c) is complete before L_c
        // and scan(c) is complete before GEMM2(c+2) reuses its buffer.
        for (int c = 0; c < n; ++c) {
            if (c + 1 < n) {
                dim3 gc(8 + (ENC * ENC) / 128, Mc / 128);
                gemm2_scan<<<gc, 256, 0, stream>>>(hidden, W2, b2,
                                                   Wab[(c + 1) & 1], Wab[c & 1],
                                                   e0, et_state, out,
                                                   chm1, chsh,
                                                   (c + 1) * CH, c * CH, CH);
            } else {
                scan_kernel<<<BB, 128, 0, stream>>>(Wab[c & 1], e0, et_state,
                                                    out, c * CH, CH);
            }
        }
        return;
    }

    // ---- Legacy serial fallback (tiny workspace): r16 behavior ----
    int CHs = 16;
    for (int c = 512; c >= 16; c >>= 1) {
        const size_t Mc = (size_t)BB * c;
        const size_t need = 4096 + Mc * HH * sizeof(float) +
                            Mc * (size_t)(ENC * ENC) * sizeof(float);
        if (need <= ws_size) { CHs = c; break; }
    }
    const int Mc = BB * CHs;
    int chsh = 0;
    while ((1 << chsh) < CHs) ++chsh;
    const int chm1 = CHs - 1;

    float* et_state = (float*)d_ws;
    float* hidden   = (float*)((char*)d_ws + 4096);
    float* Wa       = hidden + (size_t)Mc * HH;

    for (int i0 = 0; i0 < SS; i0 += CHs) {
        dim3 g1(HH / 128, Mc / 128);
        gemm_nt<1, 1, 0><<<g1, 256, 0, stream>>>(A, W1, b1, hidden, HH, EE,
                                                 chm1, chsh, i0);
        dim3 g2((ENC * ENC) / 128, Mc / 128);
        gemm_nt<0, 0, 1><<<g2, 256, 0, stream>>>(hidden, W2, b2, Wa, ENC * ENC,
                                                 HH, 0, 0, 0);
        scan_kernel<<<BB, 128, 0, stream>>>(Wa, e0, et_state, out, i0, CHs);
    }
}